// Round 1
// baseline (890.421 us; speedup 1.0000x reference)
//
#include <hip/hip_runtime.h>
#include <math.h>

#define D 128
#define PROJ_EPS 1e-5f
#define MAX_NN (1.0f - PROJ_EPS)
#define MIN_NORM 1e-15f

__device__ inline float wave_sum(float v) {
#pragma unroll
    for (int off = 32; off; off >>= 1) v += __shfl_xor(v, off, 64);
    return v;
}

// ---------------- CSR build ----------------
__global__ void hist_kernel(const int* __restrict__ rows, int* __restrict__ counts, int e) {
    int i = blockIdx.x * blockDim.x + threadIdx.x;
    if (i < e) atomicAdd(&counts[rows[i]], 1);
}

// single block, 1024 threads; each thread owns 128 consecutive rows per chunk
__global__ void scan_kernel(const int* __restrict__ counts, int* __restrict__ row_ptr,
                            int* __restrict__ cursor, int n) {
    __shared__ int wsum[16];
    __shared__ int carry_s;
    int tid = threadIdx.x;
    if (tid == 0) carry_s = 0;
    __syncthreads();
    for (int base = 0; base < n; base += 131072) {
        int carry = carry_s;
        int start = base + tid * 128;
        int total = 0;
        for (int j = 0; j < 128; ++j) {
            int i = start + j;
            if (i < n) total += counts[i];
        }
        int lane = tid & 63, wv = tid >> 6;
        int inc = total;
#pragma unroll
        for (int o = 1; o < 64; o <<= 1) {
            int t = __shfl_up(inc, o, 64);
            if (lane >= o) inc += t;
        }
        if (lane == 63) wsum[wv] = inc;
        __syncthreads();
        if (tid == 0) {
            int s = 0;
            for (int w = 0; w < 16; ++w) { int t = wsum[w]; wsum[w] = s; s += t; }
            carry_s = carry + s;
        }
        __syncthreads();
        int excl = carry + wsum[wv] + (inc - total);
        int run = excl;
        for (int j = 0; j < 128; ++j) {
            int i = start + j;
            if (i < n) {
                row_ptr[i] = run;
                cursor[i] = run;
                run += counts[i];
            }
        }
        if (start <= n - 1 && n - 1 < start + 128) row_ptr[n] = run;
        __syncthreads();
    }
}

__global__ void scatter_kernel(const int* __restrict__ rows, const int* __restrict__ cols,
                               const float* __restrict__ vals, int* __restrict__ cursor,
                               int* __restrict__ col_s, float* __restrict__ val_s, int e) {
    int i = blockIdx.x * blockDim.x + threadIdx.x;
    if (i < e) {
        int r = rows[i];
        int pos = atomicAdd(&cursor[r], 1);
        col_s[pos] = cols[i];
        val_s[pos] = vals[i];
    }
}

// ---------------- init: x = proj(ent), logscale = atanh(clip(||x||))/||x|| ----------------
__global__ __launch_bounds__(256) void proj_init(const float* __restrict__ ent,
                                                 float* __restrict__ x,
                                                 float* __restrict__ logscale, int n) {
    int wid = (int)((blockIdx.x * (size_t)blockDim.x + threadIdx.x) >> 6);
    int lane = threadIdx.x & 63;
    if (wid >= n) return;
    float2 v = *(const float2*)(ent + (size_t)wid * D + 2 * lane);
    float nrm = sqrtf(wave_sum(v.x * v.x + v.y * v.y));
    float scale = (nrm > MAX_NN) ? MAX_NN / fmaxf(nrm, MIN_NORM) : 1.0f;
    float px = v.x * scale, py = v.y * scale;
    float n2 = fmaxf(sqrtf(wave_sum(px * px + py * py)), MIN_NORM);
    float nc = fminf(fmaxf(n2, MIN_NORM), MAX_NN);
    float ls = atanhf(nc) / n2;
    *(float2*)(x + (size_t)wid * D + 2 * lane) = make_float2(px, py);
    if (lane == 0) logscale[wid] = ls;
}

// ---------------- m = (logscale[row] * x[row]) @ W ----------------
__global__ __launch_bounds__(256) void logmap_gemm(const float* __restrict__ x,
                                                   const float* __restrict__ logscale,
                                                   const float* __restrict__ W,
                                                   float* __restrict__ m, int n) {
    int row = blockIdx.x * 256 + threadIdx.x;
    if (row >= n) return;
    float ls = logscale[row];
    const float* xrow = x + (size_t)row * D;
    float* mrow = m + (size_t)row * D;

    for (int p = 0; p < 4; ++p) {  // 32 output cols per pass
        float acc[32];
#pragma unroll
        for (int j = 0; j < 32; ++j) acc[j] = 0.0f;
        for (int kc = 0; kc < 8; ++kc) {  // 16 k per chunk
            float tk[16];
#pragma unroll
            for (int j = 0; j < 16; ++j) tk[j] = xrow[kc * 16 + j] * ls;
            const float* wbase = W + (size_t)(kc * 16) * D + p * 32;
#pragma unroll
            for (int k = 0; k < 16; ++k) {
#pragma unroll
                for (int j = 0; j < 32; ++j)
                    acc[j] = fmaf(tk[k], wbase[(size_t)k * D + j], acc[j]);
            }
        }
#pragma unroll
        for (int j = 0; j < 32; j += 4)
            *(float4*)(mrow + p * 32 + j) = make_float4(acc[j], acc[j + 1], acc[j + 2], acc[j + 3]);
    }
}

// ---------------- aggregate + full hyperbolic epilogue, wave per row ----------------
__global__ __launch_bounds__(256) void aggregate(const float* __restrict__ m,
                                                 const int* __restrict__ row_ptr,
                                                 const int* __restrict__ col_s,
                                                 const float* __restrict__ val_s,
                                                 const float* __restrict__ bias_l,
                                                 float* __restrict__ x,
                                                 float* __restrict__ logscale,
                                                 int n, int use_act) {
    int wid = (int)((blockIdx.x * (size_t)blockDim.x + threadIdx.x) >> 6);
    int lane = threadIdx.x & 63;
    if (wid >= n) return;

    int beg = row_ptr[wid], end = row_ptr[wid + 1];
    float ax = 0.f, ay = 0.f;
    for (int e = beg; e < end; ++e) {
        int c = col_s[e];
        float v = val_s[e];
        float2 mv = *(const float2*)(m + (size_t)c * D + 2 * lane);
        ax = fmaf(v, mv.x, ax);
        ay = fmaf(v, mv.y, ay);
    }

    // h = proj(exp_map_zero(agg))
    float hx, hy;
    {
        float nn = fmaxf(sqrtf(wave_sum(ax * ax + ay * ay)), MIN_NORM);
        float s = tanhf(nn) / nn;
        hx = ax * s; hy = ay * s;
        float pn = sqrtf(wave_sum(hx * hx + hy * hy));
        float sc = (pn > MAX_NN) ? MAX_NN / fmaxf(pn, MIN_NORM) : 1.0f;
        hx *= sc; hy *= sc;
    }
    // bh = proj(exp_map_zero(bias))
    float bx, by;
    {
        float2 b2 = *(const float2*)(bias_l + 2 * lane);
        float nn = fmaxf(sqrtf(wave_sum(b2.x * b2.x + b2.y * b2.y)), MIN_NORM);
        float s = tanhf(nn) / nn;
        bx = b2.x * s; by = b2.y * s;
        float pn = sqrtf(wave_sum(bx * bx + by * by));
        float sc = (pn > MAX_NN) ? MAX_NN / fmaxf(pn, MIN_NORM) : 1.0f;
        bx *= sc; by *= sc;
    }
    // h = proj(mobius_add(h, bh))
    {
        float uu = wave_sum(hx * hx + hy * hy);
        float vv = wave_sum(bx * bx + by * by);
        float uv = wave_sum(hx * bx + hy * by);
        float ca = 1.f + 2.f * uv + vv;
        float cb = 1.f - uu;
        float den = fmaxf(1.f + 2.f * uv + uu * vv, MIN_NORM);
        hx = (ca * hx + cb * bx) / den;
        hy = (ca * hy + cb * by) / den;
        float pn = sqrtf(wave_sum(hx * hx + hy * hy));
        float sc = (pn > MAX_NN) ? MAX_NN / fmaxf(pn, MIN_NORM) : 1.0f;
        hx *= sc; hy *= sc;
    }
    if (use_act) {
        // h = proj(exp_map_zero(tanh(log_map_zero(h))))
        float nn = fmaxf(sqrtf(wave_sum(hx * hx + hy * hy)), MIN_NORM);
        float nc = fminf(fmaxf(nn, MIN_NORM), MAX_NN);
        float s = atanhf(nc) / nn;
        float tx = tanhf(hx * s), ty = tanhf(hy * s);
        float nn2 = fmaxf(sqrtf(wave_sum(tx * tx + ty * ty)), MIN_NORM);
        float s2 = tanhf(nn2) / nn2;
        hx = tx * s2; hy = ty * s2;
        float pn = sqrtf(wave_sum(hx * hx + hy * hy));
        float sc = (pn > MAX_NN) ? MAX_NN / fmaxf(pn, MIN_NORM) : 1.0f;
        hx *= sc; hy *= sc;
    }
    // x_new = proj(mobius_add(h, x_old)); also next-layer logscale
    float2 xo = *(const float2*)(x + (size_t)wid * D + 2 * lane);
    {
        float uu = wave_sum(hx * hx + hy * hy);
        float vv = wave_sum(xo.x * xo.x + xo.y * xo.y);
        float uv = wave_sum(hx * xo.x + hy * xo.y);
        float ca = 1.f + 2.f * uv + vv;
        float cb = 1.f - uu;
        float den = fmaxf(1.f + 2.f * uv + uu * vv, MIN_NORM);
        float ox = (ca * hx + cb * xo.x) / den;
        float oy = (ca * hy + cb * xo.y) / den;
        float pn = sqrtf(wave_sum(ox * ox + oy * oy));
        float sc = (pn > MAX_NN) ? MAX_NN / fmaxf(pn, MIN_NORM) : 1.0f;
        ox *= sc; oy *= sc;
        float nn = fmaxf(sqrtf(wave_sum(ox * ox + oy * oy)), MIN_NORM);
        float nc = fminf(fmaxf(nn, MIN_NORM), MAX_NN);
        float ls = atanhf(nc) / nn;
        *(float2*)(x + (size_t)wid * D + 2 * lane) = make_float2(ox, oy);
        if (lane == 0) logscale[wid] = ls;
    }
}

extern "C" void kernel_launch(void* const* d_in, const int* in_sizes, int n_in,
                              void* d_out, int out_size, void* d_ws, size_t ws_size,
                              hipStream_t stream) {
    const float* ent  = (const float*)d_in[0];
    const float* W    = (const float*)d_in[1];
    const float* bias = (const float*)d_in[2];
    const int* rows   = (const int*)d_in[3];
    const int* cols   = (const int*)d_in[4];
    const float* vals = (const float*)d_in[5];
    float* x = (float*)d_out;

    const int n = in_sizes[0] / D;
    const int e = in_sizes[3];
    const int nlayers = in_sizes[1] / (D * D);

    char* ws = (char*)d_ws;
    size_t off = 0;
    auto alloc = [&](size_t bytes) {
        void* p = ws + off;
        off += (bytes + 255) & ~(size_t)255;
        return p;
    };
    float* m        = (float*)alloc((size_t)n * D * sizeof(float));
    float* logscale = (float*)alloc((size_t)n * sizeof(float));
    int*   counts   = (int*)alloc((size_t)n * sizeof(int));
    int*   row_ptr  = (int*)alloc((size_t)(n + 1) * sizeof(int));
    int*   cursor   = (int*)alloc((size_t)n * sizeof(int));
    int*   col_s    = (int*)alloc((size_t)e * sizeof(int));
    float* val_s    = (float*)alloc((size_t)e * sizeof(float));

    hipMemsetAsync(counts, 0, (size_t)n * sizeof(int), stream);
    hist_kernel<<<(e + 255) / 256, 256, 0, stream>>>(rows, counts, e);
    scan_kernel<<<1, 1024, 0, stream>>>(counts, row_ptr, cursor, n);
    scatter_kernel<<<(e + 255) / 256, 256, 0, stream>>>(rows, cols, vals, cursor, col_s, val_s, e);

    proj_init<<<(n + 3) / 4, 256, 0, stream>>>(ent, x, logscale, n);

    for (int l = 0; l < nlayers; ++l) {
        logmap_gemm<<<(n + 255) / 256, 256, 0, stream>>>(x, logscale, W + (size_t)l * D * D, m, n);
        aggregate<<<(n + 3) / 4, 256, 0, stream>>>(m, row_ptr, col_s, val_s,
                                                   bias + (size_t)l * D, x, logscale, n,
                                                   (l < nlayers - 1) ? 1 : 0);
    }
}

// Round 2
// 662.701 us; speedup vs baseline: 1.3436x; 1.3436x over previous
//
#include <hip/hip_runtime.h>
#include <math.h>

#define D 128
#define PROJ_EPS 1e-5f
#define MAX_NN (1.0f - PROJ_EPS)
#define MIN_NORM 1e-15f
#define ROWS_PER_BLOCK 2048

__device__ inline float wave_sum(float v) {
#pragma unroll
    for (int off = 32; off; off >>= 1) v += __shfl_xor(v, off, 64);
    return v;
}

// ---------------- CSR build ----------------
__global__ void hist_kernel(const int* __restrict__ rows, int* __restrict__ counts, int e) {
    int i = blockIdx.x * blockDim.x + threadIdx.x;
    if (i < e) atomicAdd(&counts[rows[i]], 1);
}

// stage 1: per-block partial sums (256 thr × 8 rows = 2048 rows/block)
__global__ __launch_bounds__(256) void partial_kernel(const int* __restrict__ counts,
                                                      int* __restrict__ partials, int n) {
    int t = threadIdx.x;
    int start = blockIdx.x * ROWS_PER_BLOCK + t * 8;
    int s = 0;
#pragma unroll
    for (int j = 0; j < 8; ++j) {
        int i = start + j;
        if (i < n) s += counts[i];
    }
    int lane = t & 63, wv = t >> 6;
#pragma unroll
    for (int o = 32; o; o >>= 1) s += __shfl_xor(s, o, 64);
    __shared__ int wsum[4];
    if (lane == 0) wsum[wv] = s;
    __syncthreads();
    if (t == 0) partials[blockIdx.x] = wsum[0] + wsum[1] + wsum[2] + wsum[3];
}

// stage 2: exclusive scan of partials (npart <= 1024), single block of 1024
__global__ void scan_partials(int* __restrict__ partials, int npart) {
    __shared__ int buf[1024];
    int t = threadIdx.x;
    int v = (t < npart) ? partials[t] : 0;
    buf[t] = v;
    __syncthreads();
    for (int o = 1; o < 1024; o <<= 1) {
        int x = (t >= o) ? buf[t - o] : 0;
        __syncthreads();
        buf[t] += x;
        __syncthreads();
    }
    if (t < npart) partials[t] = buf[t] - v;  // exclusive
}

// stage 3: per-block row_ptr / cursor write
__global__ __launch_bounds__(256) void rowptr_kernel(const int* __restrict__ counts,
                                                     const int* __restrict__ partials,
                                                     int* __restrict__ row_ptr,
                                                     int* __restrict__ cursor, int n, int e) {
    int t = threadIdx.x;
    int start = blockIdx.x * ROWS_PER_BLOCK + t * 8;
    int c[8];
    int s = 0;
#pragma unroll
    for (int j = 0; j < 8; ++j) {
        int i = start + j;
        c[j] = (i < n) ? counts[i] : 0;
        s += c[j];
    }
    int lane = t & 63, wv = t >> 6;
    int inc = s;
#pragma unroll
    for (int o = 1; o < 64; o <<= 1) {
        int tt = __shfl_up(inc, o, 64);
        if (lane >= o) inc += tt;
    }
    __shared__ int wsum[4];
    if (lane == 63) wsum[wv] = inc;
    __syncthreads();
    if (t == 0) {
        int acc = 0;
        for (int w = 0; w < 4; ++w) { int tmp = wsum[w]; wsum[w] = acc; acc += tmp; }
    }
    __syncthreads();
    int run = partials[blockIdx.x] + wsum[wv] + (inc - s);
#pragma unroll
    for (int j = 0; j < 8; ++j) {
        int i = start + j;
        if (i < n) {
            row_ptr[i] = run;
            cursor[i] = run;
            run += c[j];
        }
    }
    if (blockIdx.x == 0 && t == 0) row_ptr[n] = e;
}

__global__ void scatter_kernel(const int* __restrict__ rows, const int* __restrict__ cols,
                               const float* __restrict__ vals, int* __restrict__ cursor,
                               int* __restrict__ col_s, float* __restrict__ val_s, int e) {
    int i = blockIdx.x * blockDim.x + threadIdx.x;
    if (i < e) {
        int r = rows[i];
        int pos = atomicAdd(&cursor[r], 1);
        col_s[pos] = cols[i];
        val_s[pos] = vals[i];
    }
}

// ---------------- init: x = proj(ent), logscale = atanh(clip(||x||))/||x|| ----------------
__global__ __launch_bounds__(256) void proj_init(const float* __restrict__ ent,
                                                 float* __restrict__ x,
                                                 float* __restrict__ logscale, int n) {
    int wid = (int)((blockIdx.x * (size_t)blockDim.x + threadIdx.x) >> 6);
    int lane = threadIdx.x & 63;
    if (wid >= n) return;
    float2 v = *(const float2*)(ent + (size_t)wid * D + 2 * lane);
    float nrm = sqrtf(wave_sum(v.x * v.x + v.y * v.y));
    float scale = (nrm > MAX_NN) ? MAX_NN / fmaxf(nrm, MIN_NORM) : 1.0f;
    float px = v.x * scale, py = v.y * scale;
    float n2 = fmaxf(sqrtf(wave_sum(px * px + py * py)), MIN_NORM);
    float nc = fminf(fmaxf(n2, MIN_NORM), MAX_NN);
    float ls = atanhf(nc) / n2;
    *(float2*)(x + (size_t)wid * D + 2 * lane) = make_float2(px, py);
    if (lane == 0) logscale[wid] = ls;
}

// ---------------- m = (logscale[row] * x[row]) @ W ----------------
__global__ __launch_bounds__(256) void logmap_gemm(const float* __restrict__ x,
                                                   const float* __restrict__ logscale,
                                                   const float* __restrict__ W,
                                                   float* __restrict__ m, int n) {
    int row = blockIdx.x * 256 + threadIdx.x;
    if (row >= n) return;
    float ls = logscale[row];
    const float* xrow = x + (size_t)row * D;
    float* mrow = m + (size_t)row * D;

    for (int p = 0; p < 4; ++p) {  // 32 output cols per pass
        float acc[32];
#pragma unroll
        for (int j = 0; j < 32; ++j) acc[j] = 0.0f;
        for (int kc = 0; kc < 8; ++kc) {  // 16 k per chunk
            float tk[16];
#pragma unroll
            for (int j = 0; j < 16; ++j) tk[j] = xrow[kc * 16 + j] * ls;
            const float* wbase = W + (size_t)(kc * 16) * D + p * 32;
#pragma unroll
            for (int k = 0; k < 16; ++k) {
#pragma unroll
                for (int j = 0; j < 32; ++j)
                    acc[j] = fmaf(tk[k], wbase[(size_t)k * D + j], acc[j]);
            }
        }
#pragma unroll
        for (int j = 0; j < 32; j += 4)
            *(float4*)(mrow + p * 32 + j) = make_float4(acc[j], acc[j + 1], acc[j + 2], acc[j + 3]);
    }
}

// ---------------- aggregate + full hyperbolic epilogue, wave per row ----------------
__global__ __launch_bounds__(256) void aggregate(const float* __restrict__ m,
                                                 const int* __restrict__ row_ptr,
                                                 const int* __restrict__ col_s,
                                                 const float* __restrict__ val_s,
                                                 const float* __restrict__ bias_l,
                                                 float* __restrict__ x,
                                                 float* __restrict__ logscale,
                                                 int n, int use_act) {
    int wid = (int)((blockIdx.x * (size_t)blockDim.x + threadIdx.x) >> 6);
    int lane = threadIdx.x & 63;
    if (wid >= n) return;

    int beg = row_ptr[wid], end = row_ptr[wid + 1];
    float ax = 0.f, ay = 0.f;
    for (int e = beg; e < end; ++e) {
        int c = col_s[e];
        float v = val_s[e];
        float2 mv = *(const float2*)(m + (size_t)c * D + 2 * lane);
        ax = fmaf(v, mv.x, ax);
        ay = fmaf(v, mv.y, ay);
    }

    // h = proj(exp_map_zero(agg))
    float hx, hy;
    {
        float nn = fmaxf(sqrtf(wave_sum(ax * ax + ay * ay)), MIN_NORM);
        float s = tanhf(nn) / nn;
        hx = ax * s; hy = ay * s;
        float pn = sqrtf(wave_sum(hx * hx + hy * hy));
        float sc = (pn > MAX_NN) ? MAX_NN / fmaxf(pn, MIN_NORM) : 1.0f;
        hx *= sc; hy *= sc;
    }
    // bh = proj(exp_map_zero(bias))
    float bx, by;
    {
        float2 b2 = *(const float2*)(bias_l + 2 * lane);
        float nn = fmaxf(sqrtf(wave_sum(b2.x * b2.x + b2.y * b2.y)), MIN_NORM);
        float s = tanhf(nn) / nn;
        bx = b2.x * s; by = b2.y * s;
        float pn = sqrtf(wave_sum(bx * bx + by * by));
        float sc = (pn > MAX_NN) ? MAX_NN / fmaxf(pn, MIN_NORM) : 1.0f;
        bx *= sc; by *= sc;
    }
    // h = proj(mobius_add(h, bh))
    {
        float uu = wave_sum(hx * hx + hy * hy);
        float vv = wave_sum(bx * bx + by * by);
        float uv = wave_sum(hx * bx + hy * by);
        float ca = 1.f + 2.f * uv + vv;
        float cb = 1.f - uu;
        float den = fmaxf(1.f + 2.f * uv + uu * vv, MIN_NORM);
        hx = (ca * hx + cb * bx) / den;
        hy = (ca * hy + cb * by) / den;
        float pn = sqrtf(wave_sum(hx * hx + hy * hy));
        float sc = (pn > MAX_NN) ? MAX_NN / fmaxf(pn, MIN_NORM) : 1.0f;
        hx *= sc; hy *= sc;
    }
    if (use_act) {
        // h = proj(exp_map_zero(tanh(log_map_zero(h))))
        float nn = fmaxf(sqrtf(wave_sum(hx * hx + hy * hy)), MIN_NORM);
        float nc = fminf(fmaxf(nn, MIN_NORM), MAX_NN);
        float s = atanhf(nc) / nn;
        float tx = tanhf(hx * s), ty = tanhf(hy * s);
        float nn2 = fmaxf(sqrtf(wave_sum(tx * tx + ty * ty)), MIN_NORM);
        float s2 = tanhf(nn2) / nn2;
        hx = tx * s2; hy = ty * s2;
        float pn = sqrtf(wave_sum(hx * hx + hy * hy));
        float sc = (pn > MAX_NN) ? MAX_NN / fmaxf(pn, MIN_NORM) : 1.0f;
        hx *= sc; hy *= sc;
    }
    // x_new = proj(mobius_add(h, x_old)); also next-layer logscale
    float2 xo = *(const float2*)(x + (size_t)wid * D + 2 * lane);
    {
        float uu = wave_sum(hx * hx + hy * hy);
        float vv = wave_sum(xo.x * xo.x + xo.y * xo.y);
        float uv = wave_sum(hx * xo.x + hy * xo.y);
        float ca = 1.f + 2.f * uv + vv;
        float cb = 1.f - uu;
        float den = fmaxf(1.f + 2.f * uv + uu * vv, MIN_NORM);
        float ox = (ca * hx + cb * xo.x) / den;
        float oy = (ca * hy + cb * xo.y) / den;
        float pn = sqrtf(wave_sum(ox * ox + oy * oy));
        float sc = (pn > MAX_NN) ? MAX_NN / fmaxf(pn, MIN_NORM) : 1.0f;
        ox *= sc; oy *= sc;
        float nn = fmaxf(sqrtf(wave_sum(ox * ox + oy * oy)), MIN_NORM);
        float nc = fminf(fmaxf(nn, MIN_NORM), MAX_NN);
        float ls = atanhf(nc) / nn;
        *(float2*)(x + (size_t)wid * D + 2 * lane) = make_float2(ox, oy);
        if (lane == 0) logscale[wid] = ls;
    }
}

extern "C" void kernel_launch(void* const* d_in, const int* in_sizes, int n_in,
                              void* d_out, int out_size, void* d_ws, size_t ws_size,
                              hipStream_t stream) {
    const float* ent  = (const float*)d_in[0];
    const float* W    = (const float*)d_in[1];
    const float* bias = (const float*)d_in[2];
    const int* rows   = (const int*)d_in[3];
    const int* cols   = (const int*)d_in[4];
    const float* vals = (const float*)d_in[5];
    float* x = (float*)d_out;

    const int n = in_sizes[0] / D;
    const int e = in_sizes[3];
    const int nlayers = in_sizes[1] / (D * D);
    const int npart = (n + ROWS_PER_BLOCK - 1) / ROWS_PER_BLOCK;

    char* ws = (char*)d_ws;
    size_t off = 0;
    auto alloc = [&](size_t bytes) {
        void* p = ws + off;
        off += (bytes + 255) & ~(size_t)255;
        return p;
    };
    float* m        = (float*)alloc((size_t)n * D * sizeof(float));
    float* logscale = (float*)alloc((size_t)n * sizeof(float));
    int*   counts   = (int*)alloc((size_t)n * sizeof(int));
    int*   row_ptr  = (int*)alloc((size_t)(n + 1) * sizeof(int));
    int*   cursor   = (int*)alloc((size_t)n * sizeof(int));
    int*   partials = (int*)alloc((size_t)(npart > 1024 ? npart : 1024) * sizeof(int));
    int*   col_s    = (int*)alloc((size_t)e * sizeof(int));
    float* val_s    = (float*)alloc((size_t)e * sizeof(float));

    hipMemsetAsync(counts, 0, (size_t)n * sizeof(int), stream);
    hist_kernel<<<(e + 255) / 256, 256, 0, stream>>>(rows, counts, e);
    partial_kernel<<<npart, 256, 0, stream>>>(counts, partials, n);
    scan_partials<<<1, 1024, 0, stream>>>(partials, npart);
    rowptr_kernel<<<npart, 256, 0, stream>>>(counts, partials, row_ptr, cursor, n, e);
    scatter_kernel<<<(e + 255) / 256, 256, 0, stream>>>(rows, cols, vals, cursor, col_s, val_s, e);

    proj_init<<<(n + 3) / 4, 256, 0, stream>>>(ent, x, logscale, n);

    for (int l = 0; l < nlayers; ++l) {
        logmap_gemm<<<(n + 255) / 256, 256, 0, stream>>>(x, logscale, W + (size_t)l * D * D, m, n);
        aggregate<<<(n + 3) / 4, 256, 0, stream>>>(m, row_ptr, col_s, val_s,
                                                   bias + (size_t)l * D, x, logscale, n,
                                                   (l < nlayers - 1) ? 1 : 0);
    }
}

// Round 3
// 465.338 us; speedup vs baseline: 1.9135x; 1.4241x over previous
//
#include <hip/hip_runtime.h>
#include <math.h>

#define D 128
#define PROJ_EPS 1e-5f
#define MAX_NN (1.0f - PROJ_EPS)
#define MIN_NORM 1e-15f
#define ROWS_PER_BLOCK 2048

struct __align__(8) Edge { int c; float v; };

__device__ inline float wave_sum(float v) {
#pragma unroll
    for (int off = 32; off; off >>= 1) v += __shfl_xor(v, off, 64);
    return v;
}
__device__ inline void wave_sum2(float& a, float& b) {
#pragma unroll
    for (int off = 32; off; off >>= 1) {
        a += __shfl_xor(a, off, 64);
        b += __shfl_xor(b, off, 64);
    }
}
__device__ inline float frcp(float x) { return __builtin_amdgcn_rcpf(x); }
__device__ inline float fsqrt_(float x) { return __builtin_amdgcn_sqrtf(x); }
// tanh for x >= 0
__device__ inline float tanh_pos(float x) {
    float e = __expf(-2.f * x);
    return (1.f - e) * frcp(1.f + e);
}
__device__ inline float tanh_sgn(float x) {
    float ax = fabsf(x);
    float e = __expf(-2.f * ax);
    float r = (1.f - e) * frcp(1.f + e);
    return copysignf(r, x);
}
// atanh for x in [0, 1)
__device__ inline float atanh_clip(float x) {
    return 0.5f * __logf((1.f + x) * frcp(1.f - x));
}

// ---------------- CSR build ----------------
__global__ void hist_kernel(const int* __restrict__ rows, int* __restrict__ counts, int e) {
    int i = blockIdx.x * blockDim.x + threadIdx.x;
    if (i < e) atomicAdd(&counts[rows[i]], 1);
}

__global__ __launch_bounds__(256) void partial_kernel(const int* __restrict__ counts,
                                                      int* __restrict__ partials, int n) {
    int t = threadIdx.x;
    int start = blockIdx.x * ROWS_PER_BLOCK + t * 8;
    int s = 0;
#pragma unroll
    for (int j = 0; j < 8; ++j) {
        int i = start + j;
        if (i < n) s += counts[i];
    }
    int lane = t & 63, wv = t >> 6;
#pragma unroll
    for (int o = 32; o; o >>= 1) s += __shfl_xor(s, o, 64);
    __shared__ int wsum[4];
    if (lane == 0) wsum[wv] = s;
    __syncthreads();
    if (t == 0) partials[blockIdx.x] = wsum[0] + wsum[1] + wsum[2] + wsum[3];
}

__global__ void scan_partials(int* __restrict__ partials, int npart) {
    __shared__ int buf[1024];
    int t = threadIdx.x;
    int v = (t < npart) ? partials[t] : 0;
    buf[t] = v;
    __syncthreads();
    for (int o = 1; o < 1024; o <<= 1) {
        int x = (t >= o) ? buf[t - o] : 0;
        __syncthreads();
        buf[t] += x;
        __syncthreads();
    }
    if (t < npart) partials[t] = buf[t] - v;
}

__global__ __launch_bounds__(256) void rowptr_kernel(const int* __restrict__ counts,
                                                     const int* __restrict__ partials,
                                                     int* __restrict__ row_ptr,
                                                     int* __restrict__ cursor, int n, int e) {
    int t = threadIdx.x;
    int start = blockIdx.x * ROWS_PER_BLOCK + t * 8;
    int c[8];
    int s = 0;
#pragma unroll
    for (int j = 0; j < 8; ++j) {
        int i = start + j;
        c[j] = (i < n) ? counts[i] : 0;
        s += c[j];
    }
    int lane = t & 63, wv = t >> 6;
    int inc = s;
#pragma unroll
    for (int o = 1; o < 64; o <<= 1) {
        int tt = __shfl_up(inc, o, 64);
        if (lane >= o) inc += tt;
    }
    __shared__ int wsum[4];
    if (lane == 63) wsum[wv] = inc;
    __syncthreads();
    if (t == 0) {
        int acc = 0;
        for (int w = 0; w < 4; ++w) { int tmp = wsum[w]; wsum[w] = acc; acc += tmp; }
    }
    __syncthreads();
    int run = partials[blockIdx.x] + wsum[wv] + (inc - s);
#pragma unroll
    for (int j = 0; j < 8; ++j) {
        int i = start + j;
        if (i < n) {
            row_ptr[i] = run;
            cursor[i] = run;
            run += c[j];
        }
    }
    if (blockIdx.x == 0 && t == 0) row_ptr[n] = e;
}

__global__ void scatter_kernel(const int* __restrict__ rows, const int* __restrict__ cols,
                               const float* __restrict__ vals, int* __restrict__ cursor,
                               Edge* __restrict__ eds, int e) {
    int i = blockIdx.x * blockDim.x + threadIdx.x;
    if (i < e) {
        int r = rows[i];
        int pos = atomicAdd(&cursor[r], 1);
        Edge ed; ed.c = cols[i]; ed.v = vals[i];
        eds[pos] = ed;
    }
}

// ---------------- init: x = proj(ent), logscale, xnorm2 ----------------
__global__ __launch_bounds__(256) void proj_init(const float* __restrict__ ent,
                                                 float* __restrict__ x,
                                                 float* __restrict__ logscale,
                                                 float* __restrict__ xnorm2, int n) {
    int wid = (int)((blockIdx.x * (size_t)blockDim.x + threadIdx.x) >> 6);
    int lane = threadIdx.x & 63;
    if (wid >= n) return;
    float2 v = *(const float2*)(ent + (size_t)wid * D + 2 * lane);
    float nrm = sqrtf(wave_sum(v.x * v.x + v.y * v.y));
    float scale = (nrm > MAX_NN) ? MAX_NN / fmaxf(nrm, MIN_NORM) : 1.0f;
    float px = v.x * scale, py = v.y * scale;
    float n2 = fmaxf(sqrtf(wave_sum(px * px + py * py)), MIN_NORM);
    float nc = fminf(fmaxf(n2, MIN_NORM), MAX_NN);
    float ls = atanhf(nc) / n2;
    *(float2*)(x + (size_t)wid * D + 2 * lane) = make_float2(px, py);
    if (lane == 0) { logscale[wid] = ls; xnorm2[wid] = n2 * n2; }
}

// ---------------- per-layer bias precompute: bh = proj(exp0(bias_l)), vvb = ||bh||^2 ----
__global__ void bias_prep(const float* __restrict__ bias, float* __restrict__ bh,
                          float* __restrict__ vvb) {
    int l = blockIdx.x;
    int lane = threadIdx.x;
    float2 b2 = *(const float2*)(bias + (size_t)l * D + 2 * lane);
    float nn = fmaxf(sqrtf(wave_sum(b2.x * b2.x + b2.y * b2.y)), MIN_NORM);
    float s = tanhf(nn) / nn;
    float bx = b2.x * s, by = b2.y * s;
    float pn = sqrtf(wave_sum(bx * bx + by * by));
    float sc = (pn > MAX_NN) ? MAX_NN / fmaxf(pn, MIN_NORM) : 1.0f;
    bx *= sc; by *= sc;
    float vv = wave_sum(bx * bx + by * by);
    *(float2*)(bh + (size_t)l * D + 2 * lane) = make_float2(bx, by);
    if (lane == 0) vvb[l] = vv;
}

// ---------------- m = (logscale[row] * x[row]) @ W  (LDS-tiled) ----------------
__global__ __launch_bounds__(256) void logmap_gemm(const float* __restrict__ x,
                                                   const float* __restrict__ logscale,
                                                   const float* __restrict__ W,
                                                   float* __restrict__ m, int n) {
    __shared__ float xs[128][128];   // [k][row], log-scaled
    __shared__ float wsm[128][128];  // [k][col]
    int t = threadIdx.x;
    int row0 = blockIdx.x * 128;

    {
        int r = t >> 1;            // 0..127
        int kh = (t & 1) * 64;     // 0 or 64
        int grow = row0 + r;
        float ls = (grow < n) ? logscale[grow] : 0.f;
        const float4* src = (const float4*)(x + (size_t)grow * D + kh);
        const float4* wsrc = (const float4*)(W + (size_t)r * D + kh);
        float4* wdst = (float4*)&wsm[r][kh];
#pragma unroll 4
        for (int j = 0; j < 16; ++j) {
            float4 v = (grow < n) ? src[j] : make_float4(0.f, 0.f, 0.f, 0.f);
            int k = kh + j * 4;
            xs[k][r] = v.x * ls;
            xs[k + 1][r] = v.y * ls;
            xs[k + 2][r] = v.z * ls;
            xs[k + 3][r] = v.w * ls;
            wdst[j] = wsrc[j];
        }
    }
    __syncthreads();

    int tx = t & 15, ty = t >> 4;  // 16x16 grid, 8x8 micro-tile
    float acc[8][8];
#pragma unroll
    for (int r = 0; r < 8; ++r)
#pragma unroll
        for (int c = 0; c < 8; ++c) acc[r][c] = 0.f;

#pragma unroll 4
    for (int k = 0; k < 128; ++k) {
        float a[8], b[8];
        *(float4*)&a[0] = *(const float4*)&xs[k][ty * 8];
        *(float4*)&a[4] = *(const float4*)&xs[k][ty * 8 + 4];
        *(float4*)&b[0] = *(const float4*)&wsm[k][tx * 8];
        *(float4*)&b[4] = *(const float4*)&wsm[k][tx * 8 + 4];
#pragma unroll
        for (int r = 0; r < 8; ++r)
#pragma unroll
            for (int c = 0; c < 8; ++c) acc[r][c] = fmaf(a[r], b[c], acc[r][c]);
    }

#pragma unroll
    for (int r = 0; r < 8; ++r) {
        int grow = row0 + ty * 8 + r;
        if (grow < n) {
            float4* dst = (float4*)(m + (size_t)grow * D + tx * 8);
            dst[0] = make_float4(acc[r][0], acc[r][1], acc[r][2], acc[r][3]);
            dst[1] = make_float4(acc[r][4], acc[r][5], acc[r][6], acc[r][7]);
        }
    }
}

// ---------------- aggregate + analytic-norm hyperbolic epilogue ----------------
__global__ __launch_bounds__(256) void aggregate(const float* __restrict__ m,
                                                 const int* __restrict__ row_ptr,
                                                 const Edge* __restrict__ eds,
                                                 const float* __restrict__ bh,
                                                 const float* __restrict__ vvb_p,
                                                 float* __restrict__ x,
                                                 float* __restrict__ logscale,
                                                 float* __restrict__ xnorm2,
                                                 int n, int use_act, int last) {
    int wid = (int)((blockIdx.x * (size_t)blockDim.x + threadIdx.x) >> 6);
    int lane = threadIdx.x & 63;
    if (wid >= n) return;

    int beg = row_ptr[wid], end = row_ptr[wid + 1];
    const char* mB = (const char*)m + ((size_t)lane << 3);
    float ax = 0.f, ay = 0.f;
    int e = beg;
    for (; e + 4 <= end; e += 4) {
        Edge e0 = eds[e], e1 = eds[e + 1], e2 = eds[e + 2], e3 = eds[e + 3];
        float2 m0 = *(const float2*)(mB + ((size_t)e0.c << 9));
        float2 m1 = *(const float2*)(mB + ((size_t)e1.c << 9));
        float2 m2 = *(const float2*)(mB + ((size_t)e2.c << 9));
        float2 m3 = *(const float2*)(mB + ((size_t)e3.c << 9));
        ax = fmaf(e0.v, m0.x, ax); ay = fmaf(e0.v, m0.y, ay);
        ax = fmaf(e1.v, m1.x, ax); ay = fmaf(e1.v, m1.y, ay);
        ax = fmaf(e2.v, m2.x, ax); ay = fmaf(e2.v, m2.y, ay);
        ax = fmaf(e3.v, m3.x, ax); ay = fmaf(e3.v, m3.y, ay);
    }
    for (; e < end; ++e) {
        Edge ee = eds[e];
        float2 mv = *(const float2*)(mB + ((size_t)ee.c << 9));
        ax = fmaf(ee.v, mv.x, ax); ay = fmaf(ee.v, mv.y, ay);
    }

    float2 bhv = *(const float2*)(bh + 2 * lane);
    float vvb = *vvb_p;

    // reduction 1: ||agg||^2 and agg.bh
    float saa = ax * ax + ay * ay;
    float sab = ax * bhv.x + ay * bhv.y;
    wave_sum2(saa, sab);

    // h = proj(exp0(agg)) : analytic norm
    float na = fmaxf(fsqrt_(saa), MIN_NORM);
    float th = tanh_pos(na);
    float s1 = th * frcp(na);
    float nh = th;
    if (th > MAX_NN) { s1 *= MAX_NN * frcp(th); nh = MAX_NN; }
    float hx = ax * s1, hy = ay * s1;
    float uu = nh * nh;
    float uv = s1 * sab;

    // h2 = proj(mobius(h, bh)) : analytic norm
    float ca = 1.f + 2.f * uv + vvb;
    float cb = 1.f - uu;
    float den = fmaxf(1.f + 2.f * uv + uu * vvb, MIN_NORM);
    float numx = ca * hx + cb * bhv.x;
    float numy = ca * hy + cb * bhv.y;
    float nsq = fmaxf(ca * ca * uu + 2.f * ca * cb * uv + cb * cb * vvb, 0.f);
    float rden = frcp(den);
    float n2 = fsqrt_(nsq) * rden;
    float s2 = rden;
    if (n2 > MAX_NN) { s2 *= MAX_NN * frcp(n2); n2 = MAX_NN; }
    float h2x = numx * s2, h2y = numy * s2;

    float2 xo = *(const float2*)(x + (size_t)wid * D + 2 * lane);

    float hx3, hy3, uu3, uv3;
    if (use_act) {
        // h3 = proj(exp0(tanh(log0(h2))))
        float nnv = fmaxf(n2, MIN_NORM);
        float nc = fminf(fmaxf(n2, MIN_NORM), MAX_NN);
        float ls2 = atanh_clip(nc) * frcp(nnv);
        float tx = tanh_sgn(h2x * ls2);
        float ty = tanh_sgn(h2y * ls2);
        float stt = tx * tx + ty * ty;
        float stx = tx * xo.x + ty * xo.y;
        wave_sum2(stt, stx);
        float n3 = fmaxf(fsqrt_(stt), MIN_NORM);
        float th3 = tanh_pos(n3);
        float s3 = th3 * frcp(n3);
        float nh3 = th3;
        if (th3 > MAX_NN) { s3 *= MAX_NN * frcp(th3); nh3 = MAX_NN; }
        hx3 = tx * s3; hy3 = ty * s3;
        uu3 = nh3 * nh3;
        uv3 = s3 * stx;
    } else {
        float suv = wave_sum(h2x * xo.x + h2y * xo.y);
        hx3 = h2x; hy3 = h2y;
        uu3 = n2 * n2;
        uv3 = suv;
    }

    // x_new = proj(mobius(h3, x_old)) : analytic norm
    float vv = xnorm2[wid];
    ca = 1.f + 2.f * uv3 + vv;
    cb = 1.f - uu3;
    den = fmaxf(1.f + 2.f * uv3 + uu3 * vv, MIN_NORM);
    numx = ca * hx3 + cb * xo.x;
    numy = ca * hy3 + cb * xo.y;
    nsq = fmaxf(ca * ca * uu3 + 2.f * ca * cb * uv3 + cb * cb * vv, 0.f);
    rden = frcp(den);
    float n4 = fsqrt_(nsq) * rden;
    float s4 = rden;
    if (n4 > MAX_NN) { s4 *= MAX_NN * frcp(n4); n4 = MAX_NN; }
    float oxv = numx * s4, oyv = numy * s4;

    *(float2*)(x + (size_t)wid * D + 2 * lane) = make_float2(oxv, oyv);
    if (lane == 0) {
        xnorm2[wid] = n4 * n4;
        if (!last) {
            float nnv = fmaxf(n4, MIN_NORM);
            float nc = fminf(fmaxf(n4, MIN_NORM), MAX_NN);
            logscale[wid] = atanh_clip(nc) * frcp(nnv);
        }
    }
}

extern "C" void kernel_launch(void* const* d_in, const int* in_sizes, int n_in,
                              void* d_out, int out_size, void* d_ws, size_t ws_size,
                              hipStream_t stream) {
    const float* ent  = (const float*)d_in[0];
    const float* W    = (const float*)d_in[1];
    const float* bias = (const float*)d_in[2];
    const int* rows   = (const int*)d_in[3];
    const int* cols   = (const int*)d_in[4];
    const float* vals = (const float*)d_in[5];
    float* x = (float*)d_out;

    const int n = in_sizes[0] / D;
    const int e = in_sizes[3];
    const int nlayers = in_sizes[1] / (D * D);
    const int npart = (n + ROWS_PER_BLOCK - 1) / ROWS_PER_BLOCK;

    char* ws = (char*)d_ws;
    size_t off = 0;
    auto alloc = [&](size_t bytes) {
        void* p = ws + off;
        off += (bytes + 255) & ~(size_t)255;
        return p;
    };
    float* m        = (float*)alloc((size_t)n * D * sizeof(float));
    float* logscale = (float*)alloc((size_t)n * sizeof(float));
    float* xnorm2   = (float*)alloc((size_t)n * sizeof(float));
    int*   counts   = (int*)alloc((size_t)n * sizeof(int));
    int*   row_ptr  = (int*)alloc((size_t)(n + 1) * sizeof(int));
    int*   cursor   = (int*)alloc((size_t)n * sizeof(int));
    int*   partials = (int*)alloc((size_t)(npart > 1024 ? npart : 1024) * sizeof(int));
    float* bh       = (float*)alloc((size_t)nlayers * D * sizeof(float));
    float* vvb      = (float*)alloc((size_t)nlayers * sizeof(float));
    Edge*  eds      = (Edge*)alloc((size_t)e * sizeof(Edge));

    hipMemsetAsync(counts, 0, (size_t)n * sizeof(int), stream);
    hist_kernel<<<(e + 255) / 256, 256, 0, stream>>>(rows, counts, e);
    partial_kernel<<<npart, 256, 0, stream>>>(counts, partials, n);
    scan_partials<<<1, 1024, 0, stream>>>(partials, npart);
    rowptr_kernel<<<npart, 256, 0, stream>>>(counts, partials, row_ptr, cursor, n, e);
    scatter_kernel<<<(e + 255) / 256, 256, 0, stream>>>(rows, cols, vals, cursor, eds, e);

    bias_prep<<<nlayers, 64, 0, stream>>>(bias, bh, vvb);
    proj_init<<<(n + 3) / 4, 256, 0, stream>>>(ent, x, logscale, xnorm2, n);

    for (int l = 0; l < nlayers; ++l) {
        logmap_gemm<<<(n + 127) / 128, 256, 0, stream>>>(x, logscale, W + (size_t)l * D * D, m, n);
        int use_act = (l < nlayers - 1) ? 1 : 0;
        aggregate<<<(n + 3) / 4, 256, 0, stream>>>(m, row_ptr, eds, bh + (size_t)l * D,
                                                   vvb + l, x, logscale, xnorm2, n,
                                                   use_act, (l == nlayers - 1) ? 1 : 0);
    }
}

// Round 4
// 347.227 us; speedup vs baseline: 2.5644x; 1.3402x over previous
//
#include <hip/hip_runtime.h>
#include <math.h>

#define D 128
#define PROJ_EPS 1e-5f
#define MAX_NN (1.0f - PROJ_EPS)
#define MIN_NORM 1e-15f
#define ROWS_PER_BLOCK 2048

struct __align__(8) Edge { int c; float v; };

typedef __attribute__((ext_vector_type(8))) short bf16x8;
typedef __attribute__((ext_vector_type(4))) float f32x4;

__device__ inline unsigned short f2bf(float f) {
    unsigned u = __float_as_uint(f);
    unsigned r = (u + 0x7FFFu + ((u >> 16) & 1u)) >> 16;
    return (unsigned short)r;
}
__device__ inline float bf2f(unsigned short h) {
    return __uint_as_float(((unsigned)h) << 16);
}

__device__ inline float wave_sum(float v) {
#pragma unroll
    for (int off = 32; off; off >>= 1) v += __shfl_xor(v, off, 64);
    return v;
}
__device__ inline void wave_sum2(float& a, float& b) {
#pragma unroll
    for (int off = 32; off; off >>= 1) {
        a += __shfl_xor(a, off, 64);
        b += __shfl_xor(b, off, 64);
    }
}
__device__ inline float frcp(float x) { return __builtin_amdgcn_rcpf(x); }
__device__ inline float fsqrt_(float x) { return __builtin_amdgcn_sqrtf(x); }
__device__ inline float tanh_pos(float x) {
    float e = __expf(-2.f * x);
    return (1.f - e) * frcp(1.f + e);
}
__device__ inline float tanh_sgn(float x) {
    float ax = fabsf(x);
    float e = __expf(-2.f * ax);
    float r = (1.f - e) * frcp(1.f + e);
    return copysignf(r, x);
}
__device__ inline float atanh_clip(float x) {
    return 0.5f * __logf((1.f + x) * frcp(1.f - x));
}

// ---------------- CSR build ----------------
__global__ void hist_kernel(const int* __restrict__ rows, int* __restrict__ counts, int e) {
    int i = blockIdx.x * blockDim.x + threadIdx.x;
    if (i < e) atomicAdd(&counts[rows[i]], 1);
}

__global__ __launch_bounds__(256) void partial_kernel(const int* __restrict__ counts,
                                                      int* __restrict__ partials, int n) {
    int t = threadIdx.x;
    int start = blockIdx.x * ROWS_PER_BLOCK + t * 8;
    int s = 0;
#pragma unroll
    for (int j = 0; j < 8; ++j) {
        int i = start + j;
        if (i < n) s += counts[i];
    }
    int lane = t & 63, wv = t >> 6;
#pragma unroll
    for (int o = 32; o; o >>= 1) s += __shfl_xor(s, o, 64);
    __shared__ int wsum[4];
    if (lane == 0) wsum[wv] = s;
    __syncthreads();
    if (t == 0) partials[blockIdx.x] = wsum[0] + wsum[1] + wsum[2] + wsum[3];
}

__global__ void scan_partials(int* __restrict__ partials, int npart) {
    __shared__ int buf[1024];
    int t = threadIdx.x;
    int v = (t < npart) ? partials[t] : 0;
    buf[t] = v;
    __syncthreads();
    for (int o = 1; o < 1024; o <<= 1) {
        int x = (t >= o) ? buf[t - o] : 0;
        __syncthreads();
        buf[t] += x;
        __syncthreads();
    }
    if (t < npart) partials[t] = buf[t] - v;
}

__global__ __launch_bounds__(256) void rowptr_kernel(const int* __restrict__ counts,
                                                     const int* __restrict__ partials,
                                                     int* __restrict__ row_ptr,
                                                     int* __restrict__ cursor, int n, int e) {
    int t = threadIdx.x;
    int start = blockIdx.x * ROWS_PER_BLOCK + t * 8;
    int c[8];
    int s = 0;
#pragma unroll
    for (int j = 0; j < 8; ++j) {
        int i = start + j;
        c[j] = (i < n) ? counts[i] : 0;
        s += c[j];
    }
    int lane = t & 63, wv = t >> 6;
    int inc = s;
#pragma unroll
    for (int o = 1; o < 64; o <<= 1) {
        int tt = __shfl_up(inc, o, 64);
        if (lane >= o) inc += tt;
    }
    __shared__ int wsum[4];
    if (lane == 63) wsum[wv] = inc;
    __syncthreads();
    if (t == 0) {
        int acc = 0;
        for (int w = 0; w < 4; ++w) { int tmp = wsum[w]; wsum[w] = acc; acc += tmp; }
    }
    __syncthreads();
    int run = partials[blockIdx.x] + wsum[wv] + (inc - s);
#pragma unroll
    for (int j = 0; j < 8; ++j) {
        int i = start + j;
        if (i < n) {
            row_ptr[i] = run;
            cursor[i] = run;
            run += c[j];
        }
    }
    if (blockIdx.x == 0 && t == 0) row_ptr[n] = e;
}

__global__ void scatter_kernel(const int* __restrict__ rows, const int* __restrict__ cols,
                               const float* __restrict__ vals, int* __restrict__ cursor,
                               Edge* __restrict__ eds, int e) {
    int i = blockIdx.x * blockDim.x + threadIdx.x;
    if (i < e) {
        int r = rows[i];
        int pos = atomicAdd(&cursor[r], 1);
        Edge ed; ed.c = cols[i]; ed.v = vals[i];
        eds[pos] = ed;
    }
}

// ---------------- init: x = proj(ent), logscale, xnorm2 ----------------
__global__ __launch_bounds__(256) void proj_init(const float* __restrict__ ent,
                                                 float* __restrict__ x,
                                                 float* __restrict__ logscale,
                                                 float* __restrict__ xnorm2, int n) {
    int wid = (int)((blockIdx.x * (size_t)blockDim.x + threadIdx.x) >> 6);
    int lane = threadIdx.x & 63;
    if (wid >= n) return;
    float2 v = *(const float2*)(ent + (size_t)wid * D + 2 * lane);
    float nrm = sqrtf(wave_sum(v.x * v.x + v.y * v.y));
    float scale = (nrm > MAX_NN) ? MAX_NN / fmaxf(nrm, MIN_NORM) : 1.0f;
    float px = v.x * scale, py = v.y * scale;
    float n2 = fmaxf(sqrtf(wave_sum(px * px + py * py)), MIN_NORM);
    float nc = fminf(fmaxf(n2, MIN_NORM), MAX_NN);
    float ls = atanhf(nc) / n2;
    *(float2*)(x + (size_t)wid * D + 2 * lane) = make_float2(px, py);
    if (lane == 0) { logscale[wid] = ls; xnorm2[wid] = n2 * n2; }
}

// ---------------- per-layer bias precompute ----------------
__global__ void bias_prep(const float* __restrict__ bias, float* __restrict__ bh,
                          float* __restrict__ vvb) {
    int l = blockIdx.x;
    int lane = threadIdx.x;
    float2 b2 = *(const float2*)(bias + (size_t)l * D + 2 * lane);
    float nn = fmaxf(sqrtf(wave_sum(b2.x * b2.x + b2.y * b2.y)), MIN_NORM);
    float s = tanhf(nn) / nn;
    float bx = b2.x * s, by = b2.y * s;
    float pn = sqrtf(wave_sum(bx * bx + by * by));
    float sc = (pn > MAX_NN) ? MAX_NN / fmaxf(pn, MIN_NORM) : 1.0f;
    bx *= sc; by *= sc;
    float vv = wave_sum(bx * bx + by * by);
    *(float2*)(bh + (size_t)l * D + 2 * lane) = make_float2(bx, by);
    if (lane == 0) vvb[l] = vv;
}

// ---------------- m = (logscale[row] * x[row]) @ W via bf16 MFMA (hi/lo compensated) ----
// 256 thr = 4 waves; wave w owns cols [w*32, w*32+32). Tile = 32 rows, full K=128.
// W frags in regs (loaded once per block). x tile staged fragment-ordered in LDS:
// frag fi = rf*4+ki; hi at fi*1024 + lane*16, lo at +8192. All LDS ops lane-linear.
__global__ __launch_bounds__(256, 3) void logmap_gemm(const float* __restrict__ x,
                                                      const float* __restrict__ logscale,
                                                      const float* __restrict__ W,
                                                      float* __restrict__ m, int n,
                                                      int ntiles) {
    __shared__ char lds[16384];
    const int t = threadIdx.x;
    const int wid = t >> 6, lane = t & 63;
    const int lcol = lane & 15, lkg = lane >> 4;
    const int colbase = wid * 32;

    // ---- B (W) fragments: bh/bl[ki][cf], col = colbase+cf*16+lcol, k = ki*32+lkg*8+e
    bf16x8 Bh[4][2], Bl[4][2];
#pragma unroll
    for (int ki = 0; ki < 4; ++ki) {
#pragma unroll
        for (int cf = 0; cf < 2; ++cf) {
            const float* wp = W + (size_t)(ki * 32 + lkg * 8) * D + colbase + cf * 16 + lcol;
#pragma unroll
            for (int e = 0; e < 8; ++e) {
                float f = wp[(size_t)e * D];
                unsigned short h = f2bf(f);
                Bh[ki][cf][e] = (short)h;
                Bl[ki][cf][e] = (short)f2bf(f - bf2f(h));
            }
        }
    }

    for (int tile = blockIdx.x; tile < ntiles; tile += gridDim.x) {
        const int row0 = tile * 32;
        __syncthreads();  // protect LDS from previous iteration's readers
        // ---- stage x tile (hi/lo), fragment-ordered
#pragma unroll
        for (int p = t; p < 512; p += 256) {
            int fi = p >> 6, ln = p & 63;
            int rf = fi >> 2, ki = fi & 3;
            int row = row0 + rf * 16 + (ln & 15);
            int k0 = ki * 32 + (ln >> 4) * 8;
            float v[8];
            if (row < n) {
                float ls = logscale[row];
                const float* xp = x + (size_t)row * D + k0;
                *(float4*)&v[0] = *(const float4*)xp;
                *(float4*)&v[4] = *(const float4*)(xp + 4);
#pragma unroll
                for (int e = 0; e < 8; ++e) v[e] *= ls;
            } else {
#pragma unroll
                for (int e = 0; e < 8; ++e) v[e] = 0.f;
            }
            bf16x8 hi, lo;
#pragma unroll
            for (int e = 0; e < 8; ++e) {
                unsigned short h = f2bf(v[e]);
                hi[e] = (short)h;
                lo[e] = (short)f2bf(v[e] - bf2f(h));
            }
            *(bf16x8*)(lds + fi * 1024 + ln * 16) = hi;
            *(bf16x8*)(lds + 8192 + fi * 1024 + ln * 16) = lo;
        }
        __syncthreads();

        // ---- MFMA: acc[rf][cf], D = Ah*Bh + Ah*Bl + Al*Bh
        f32x4 acc[2][2];
#pragma unroll
        for (int rf = 0; rf < 2; ++rf)
#pragma unroll
            for (int cf = 0; cf < 2; ++cf) acc[rf][cf] = (f32x4){0.f, 0.f, 0.f, 0.f};

#pragma unroll
        for (int ki = 0; ki < 4; ++ki) {
            bf16x8 Ah[2], Al[2];
#pragma unroll
            for (int rf = 0; rf < 2; ++rf) {
                Ah[rf] = *(const bf16x8*)(lds + (rf * 4 + ki) * 1024 + lane * 16);
                Al[rf] = *(const bf16x8*)(lds + 8192 + (rf * 4 + ki) * 1024 + lane * 16);
            }
#pragma unroll
            for (int rf = 0; rf < 2; ++rf)
#pragma unroll
                for (int cf = 0; cf < 2; ++cf) {
                    acc[rf][cf] = __builtin_amdgcn_mfma_f32_16x16x32_bf16(Ah[rf], Bh[ki][cf], acc[rf][cf], 0, 0, 0);
                    acc[rf][cf] = __builtin_amdgcn_mfma_f32_16x16x32_bf16(Ah[rf], Bl[ki][cf], acc[rf][cf], 0, 0, 0);
                    acc[rf][cf] = __builtin_amdgcn_mfma_f32_16x16x32_bf16(Al[rf], Bh[ki][cf], acc[rf][cf], 0, 0, 0);
                }
        }

        // ---- store: C row = rf*16 + lkg*4 + r, col = colbase + cf*16 + lcol
#pragma unroll
        for (int rf = 0; rf < 2; ++rf)
#pragma unroll
            for (int cf = 0; cf < 2; ++cf)
#pragma unroll
                for (int r = 0; r < 4; ++r) {
                    int row = row0 + rf * 16 + lkg * 4 + r;
                    if (row < n) m[(size_t)row * D + colbase + cf * 16 + lcol] = acc[rf][cf][r];
                }
    }
}

// ---------------- aggregate + analytic-norm hyperbolic epilogue ----------------
__global__ __launch_bounds__(256) void aggregate(const float* __restrict__ m,
                                                 const int* __restrict__ row_ptr,
                                                 const Edge* __restrict__ eds,
                                                 const float* __restrict__ bh,
                                                 const float* __restrict__ vvb_p,
                                                 float* __restrict__ x,
                                                 float* __restrict__ logscale,
                                                 float* __restrict__ xnorm2,
                                                 int n, int use_act, int last) {
    int wid = (int)((blockIdx.x * (size_t)blockDim.x + threadIdx.x) >> 6);
    int lane = threadIdx.x & 63;
    if (wid >= n) return;

    int beg = row_ptr[wid], end = row_ptr[wid + 1];
    const char* mB = (const char*)m + ((size_t)lane << 3);
    float ax = 0.f, ay = 0.f;
    int e = beg;
    for (; e + 4 <= end; e += 4) {
        Edge e0 = eds[e], e1 = eds[e + 1], e2 = eds[e + 2], e3 = eds[e + 3];
        float2 m0 = *(const float2*)(mB + ((size_t)e0.c << 9));
        float2 m1 = *(const float2*)(mB + ((size_t)e1.c << 9));
        float2 m2 = *(const float2*)(mB + ((size_t)e2.c << 9));
        float2 m3 = *(const float2*)(mB + ((size_t)e3.c << 9));
        ax = fmaf(e0.v, m0.x, ax); ay = fmaf(e0.v, m0.y, ay);
        ax = fmaf(e1.v, m1.x, ax); ay = fmaf(e1.v, m1.y, ay);
        ax = fmaf(e2.v, m2.x, ax); ay = fmaf(e2.v, m2.y, ay);
        ax = fmaf(e3.v, m3.x, ax); ay = fmaf(e3.v, m3.y, ay);
    }
    for (; e < end; ++e) {
        Edge ee = eds[e];
        float2 mv = *(const float2*)(mB + ((size_t)ee.c << 9));
        ax = fmaf(ee.v, mv.x, ax); ay = fmaf(ee.v, mv.y, ay);
    }

    float2 bhv = *(const float2*)(bh + 2 * lane);
    float vvb = *vvb_p;

    float saa = ax * ax + ay * ay;
    float sab = ax * bhv.x + ay * bhv.y;
    wave_sum2(saa, sab);

    float na = fmaxf(fsqrt_(saa), MIN_NORM);
    float th = tanh_pos(na);
    float s1 = th * frcp(na);
    float nh = th;
    if (th > MAX_NN) { s1 *= MAX_NN * frcp(th); nh = MAX_NN; }
    float hx = ax * s1, hy = ay * s1;
    float uu = nh * nh;
    float uv = s1 * sab;

    float ca = 1.f + 2.f * uv + vvb;
    float cb = 1.f - uu;
    float den = fmaxf(1.f + 2.f * uv + uu * vvb, MIN_NORM);
    float numx = ca * hx + cb * bhv.x;
    float numy = ca * hy + cb * bhv.y;
    float nsq = fmaxf(ca * ca * uu + 2.f * ca * cb * uv + cb * cb * vvb, 0.f);
    float rden = frcp(den);
    float n2 = fsqrt_(nsq) * rden;
    float s2 = rden;
    if (n2 > MAX_NN) { s2 *= MAX_NN * frcp(n2); n2 = MAX_NN; }
    float h2x = numx * s2, h2y = numy * s2;

    float2 xo = *(const float2*)(x + (size_t)wid * D + 2 * lane);

    float hx3, hy3, uu3, uv3;
    if (use_act) {
        float nnv = fmaxf(n2, MIN_NORM);
        float nc = fminf(fmaxf(n2, MIN_NORM), MAX_NN);
        float ls2 = atanh_clip(nc) * frcp(nnv);
        float tx = tanh_sgn(h2x * ls2);
        float ty = tanh_sgn(h2y * ls2);
        float stt = tx * tx + ty * ty;
        float stx = tx * xo.x + ty * xo.y;
        wave_sum2(stt, stx);
        float n3 = fmaxf(fsqrt_(stt), MIN_NORM);
        float th3 = tanh_pos(n3);
        float s3 = th3 * frcp(n3);
        float nh3 = th3;
        if (th3 > MAX_NN) { s3 *= MAX_NN * frcp(th3); nh3 = MAX_NN; }
        hx3 = tx * s3; hy3 = ty * s3;
        uu3 = nh3 * nh3;
        uv3 = s3 * stx;
    } else {
        float suv = wave_sum(h2x * xo.x + h2y * xo.y);
        hx3 = h2x; hy3 = h2y;
        uu3 = n2 * n2;
        uv3 = suv;
    }

    float vv = xnorm2[wid];
    ca = 1.f + 2.f * uv3 + vv;
    cb = 1.f - uu3;
    den = fmaxf(1.f + 2.f * uv3 + uu3 * vv, MIN_NORM);
    numx = ca * hx3 + cb * xo.x;
    numy = ca * hy3 + cb * xo.y;
    nsq = fmaxf(ca * ca * uu3 + 2.f * ca * cb * uv3 + cb * cb * vv, 0.f);
    rden = frcp(den);
    float n4 = fsqrt_(nsq) * rden;
    float s4 = rden;
    if (n4 > MAX_NN) { s4 *= MAX_NN * frcp(n4); n4 = MAX_NN; }
    float oxv = numx * s4, oyv = numy * s4;

    *(float2*)(x + (size_t)wid * D + 2 * lane) = make_float2(oxv, oyv);
    if (lane == 0) {
        xnorm2[wid] = n4 * n4;
        if (!last) {
            float nnv = fmaxf(n4, MIN_NORM);
            float nc = fminf(fmaxf(n4, MIN_NORM), MAX_NN);
            logscale[wid] = atanh_clip(nc) * frcp(nnv);
        }
    }
}

extern "C" void kernel_launch(void* const* d_in, const int* in_sizes, int n_in,
                              void* d_out, int out_size, void* d_ws, size_t ws_size,
                              hipStream_t stream) {
    const float* ent  = (const float*)d_in[0];
    const float* W    = (const float*)d_in[1];
    const float* bias = (const float*)d_in[2];
    const int* rows   = (const int*)d_in[3];
    const int* cols   = (const int*)d_in[4];
    const float* vals = (const float*)d_in[5];
    float* x = (float*)d_out;

    const int n = in_sizes[0] / D;
    const int e = in_sizes[3];
    const int nlayers = in_sizes[1] / (D * D);
    const int npart = (n + ROWS_PER_BLOCK - 1) / ROWS_PER_BLOCK;
    const int ntiles = (n + 31) / 32;

    char* ws = (char*)d_ws;
    size_t off = 0;
    auto alloc = [&](size_t bytes) {
        void* p = ws + off;
        off += (bytes + 255) & ~(size_t)255;
        return p;
    };
    float* m        = (float*)alloc((size_t)n * D * sizeof(float));
    float* logscale = (float*)alloc((size_t)n * sizeof(float));
    float* xnorm2   = (float*)alloc((size_t)n * sizeof(float));
    int*   counts   = (int*)alloc((size_t)n * sizeof(int));
    int*   row_ptr  = (int*)alloc((size_t)(n + 1) * sizeof(int));
    int*   cursor   = (int*)alloc((size_t)n * sizeof(int));
    int*   partials = (int*)alloc((size_t)(npart > 1024 ? npart : 1024) * sizeof(int));
    float* bhb      = (float*)alloc((size_t)nlayers * D * sizeof(float));
    float* vvb      = (float*)alloc((size_t)nlayers * sizeof(float));
    Edge*  eds      = (Edge*)alloc((size_t)e * sizeof(Edge));

    hipMemsetAsync(counts, 0, (size_t)n * sizeof(int), stream);
    hist_kernel<<<(e + 255) / 256, 256, 0, stream>>>(rows, counts, e);
    partial_kernel<<<npart, 256, 0, stream>>>(counts, partials, n);
    scan_partials<<<1, 1024, 0, stream>>>(partials, npart);
    rowptr_kernel<<<npart, 256, 0, stream>>>(counts, partials, row_ptr, cursor, n, e);
    scatter_kernel<<<(e + 255) / 256, 256, 0, stream>>>(rows, cols, vals, cursor, eds, e);

    bias_prep<<<nlayers, 64, 0, stream>>>(bias, bhb, vvb);
    proj_init<<<(n + 3) / 4, 256, 0, stream>>>(ent, x, logscale, xnorm2, n);

    for (int l = 0; l < nlayers; ++l) {
        logmap_gemm<<<782, 256, 0, stream>>>(x, logscale, W + (size_t)l * D * D, m, n, ntiles);
        int use_act = (l < nlayers - 1) ? 1 : 0;
        aggregate<<<(n + 3) / 4, 256, 0, stream>>>(m, row_ptr, eds, bhb + (size_t)l * D,
                                                   vvb + l, x, logscale, xnorm2, n,
                                                   use_act, (l == nlayers - 1) ? 1 : 0);
    }
}

// Round 5
// 288.071 us; speedup vs baseline: 3.0910x; 1.2054x over previous
//
#include <hip/hip_runtime.h>
#include <math.h>

#define D 128
#define PROJ_EPS 1e-5f
#define MAX_NN (1.0f - PROJ_EPS)
#define MIN_NORM 1e-15f
#define ROWS_PER_BLOCK 2048

struct __align__(8) Edge { int c; float v; };

typedef __attribute__((ext_vector_type(8))) short bf16x8;
typedef __attribute__((ext_vector_type(4))) float f32x4;

__device__ inline unsigned short f2bf(float f) {
    unsigned u = __float_as_uint(f);
    unsigned r = (u + 0x7FFFu + ((u >> 16) & 1u)) >> 16;
    return (unsigned short)r;
}
__device__ inline float bf2f(unsigned short h) {
    return __uint_as_float(((unsigned)h) << 16);
}

__device__ inline float wave_sum(float v) {
#pragma unroll
    for (int off = 32; off; off >>= 1) v += __shfl_xor(v, off, 64);
    return v;
}
// 32-lane-group reductions (xor offsets <32 never cross the half boundary)
__device__ inline float gsum(float v) {
#pragma unroll
    for (int off = 16; off; off >>= 1) v += __shfl_xor(v, off, 64);
    return v;
}
__device__ inline void gsum2(float& a, float& b) {
#pragma unroll
    for (int off = 16; off; off >>= 1) {
        a += __shfl_xor(a, off, 64);
        b += __shfl_xor(b, off, 64);
    }
}
__device__ inline float frcp(float x) { return __builtin_amdgcn_rcpf(x); }
__device__ inline float fsqrt_(float x) { return __builtin_amdgcn_sqrtf(x); }
__device__ inline float tanh_pos(float x) {
    float e = __expf(-2.f * x);
    return (1.f - e) * frcp(1.f + e);
}
__device__ inline float tanh_sgn(float x) {
    float ax = fabsf(x);
    float e = __expf(-2.f * ax);
    float r = (1.f - e) * frcp(1.f + e);
    return copysignf(r, x);
}
__device__ inline float atanh_clip(float x) {
    return 0.5f * __logf((1.f + x) * frcp(1.f - x));
}
// 4 bf16 (packed in uint2) fma into 4 accumulators
__device__ inline void bf4_fma(uint2 g, float v, float& a0, float& a1, float& a2, float& a3) {
    float f0 = __uint_as_float(g.x << 16);
    float f1 = __uint_as_float(g.x & 0xffff0000u);
    float f2 = __uint_as_float(g.y << 16);
    float f3 = __uint_as_float(g.y & 0xffff0000u);
    a0 = fmaf(v, f0, a0); a1 = fmaf(v, f1, a1);
    a2 = fmaf(v, f2, a2); a3 = fmaf(v, f3, a3);
}

// ---------------- CSR build ----------------
__global__ void hist_kernel(const int* __restrict__ rows, int* __restrict__ counts, int e) {
    int i = blockIdx.x * blockDim.x + threadIdx.x;
    if (i < e) atomicAdd(&counts[rows[i]], 1);
}

__global__ __launch_bounds__(256) void partial_kernel(const int* __restrict__ counts,
                                                      int* __restrict__ partials, int n) {
    int t = threadIdx.x;
    int start = blockIdx.x * ROWS_PER_BLOCK + t * 8;
    int s = 0;
#pragma unroll
    for (int j = 0; j < 8; ++j) {
        int i = start + j;
        if (i < n) s += counts[i];
    }
    int lane = t & 63, wv = t >> 6;
#pragma unroll
    for (int o = 32; o; o >>= 1) s += __shfl_xor(s, o, 64);
    __shared__ int wsum[4];
    if (lane == 0) wsum[wv] = s;
    __syncthreads();
    if (t == 0) partials[blockIdx.x] = wsum[0] + wsum[1] + wsum[2] + wsum[3];
}

__global__ void scan_partials(int* __restrict__ partials, int npart) {
    __shared__ int buf[1024];
    int t = threadIdx.x;
    int v = (t < npart) ? partials[t] : 0;
    buf[t] = v;
    __syncthreads();
    for (int o = 1; o < 1024; o <<= 1) {
        int x = (t >= o) ? buf[t - o] : 0;
        __syncthreads();
        buf[t] += x;
        __syncthreads();
    }
    if (t < npart) partials[t] = buf[t] - v;
}

__global__ __launch_bounds__(256) void rowptr_kernel(const int* __restrict__ counts,
                                                     const int* __restrict__ partials,
                                                     int* __restrict__ row_ptr,
                                                     int* __restrict__ cursor, int n, int e) {
    int t = threadIdx.x;
    int start = blockIdx.x * ROWS_PER_BLOCK + t * 8;
    int c[8];
    int s = 0;
#pragma unroll
    for (int j = 0; j < 8; ++j) {
        int i = start + j;
        c[j] = (i < n) ? counts[i] : 0;
        s += c[j];
    }
    int lane = t & 63, wv = t >> 6;
    int inc = s;
#pragma unroll
    for (int o = 1; o < 64; o <<= 1) {
        int tt = __shfl_up(inc, o, 64);
        if (lane >= o) inc += tt;
    }
    __shared__ int wsum[4];
    if (lane == 63) wsum[wv] = inc;
    __syncthreads();
    if (t == 0) {
        int acc = 0;
        for (int w = 0; w < 4; ++w) { int tmp = wsum[w]; wsum[w] = acc; acc += tmp; }
    }
    __syncthreads();
    int run = partials[blockIdx.x] + wsum[wv] + (inc - s);
#pragma unroll
    for (int j = 0; j < 8; ++j) {
        int i = start + j;
        if (i < n) {
            row_ptr[i] = run;
            cursor[i] = run;
            run += c[j];
        }
    }
    if (blockIdx.x == 0 && t == 0) row_ptr[n] = e;
}

__global__ void scatter_kernel(const int* __restrict__ rows, const int* __restrict__ cols,
                               const float* __restrict__ vals, int* __restrict__ cursor,
                               Edge* __restrict__ eds, int e) {
    int i = blockIdx.x * blockDim.x + threadIdx.x;
    if (i < e) {
        int r = rows[i];
        int pos = atomicAdd(&cursor[r], 1);
        Edge ed; ed.c = cols[i]; ed.v = vals[i];
        eds[pos] = ed;
    }
}

// ---------------- init: x = proj(ent), logscale, xnorm2 ----------------
__global__ __launch_bounds__(256) void proj_init(const float* __restrict__ ent,
                                                 float* __restrict__ x,
                                                 float* __restrict__ logscale,
                                                 float* __restrict__ xnorm2, int n) {
    int wid = (int)((blockIdx.x * (size_t)blockDim.x + threadIdx.x) >> 6);
    int lane = threadIdx.x & 63;
    if (wid >= n) return;
    float2 v = *(const float2*)(ent + (size_t)wid * D + 2 * lane);
    float nrm = sqrtf(wave_sum(v.x * v.x + v.y * v.y));
    float scale = (nrm > MAX_NN) ? MAX_NN / fmaxf(nrm, MIN_NORM) : 1.0f;
    float px = v.x * scale, py = v.y * scale;
    float n2 = fmaxf(sqrtf(wave_sum(px * px + py * py)), MIN_NORM);
    float nc = fminf(fmaxf(n2, MIN_NORM), MAX_NN);
    float ls = atanhf(nc) / n2;
    *(float2*)(x + (size_t)wid * D + 2 * lane) = make_float2(px, py);
    if (lane == 0) { logscale[wid] = ls; xnorm2[wid] = n2 * n2; }
}

// ---------------- per-layer bias precompute ----------------
__global__ void bias_prep(const float* __restrict__ bias, float* __restrict__ bh,
                          float* __restrict__ vvb) {
    int l = blockIdx.x;
    int lane = threadIdx.x;
    float2 b2 = *(const float2*)(bias + (size_t)l * D + 2 * lane);
    float nn = fmaxf(sqrtf(wave_sum(b2.x * b2.x + b2.y * b2.y)), MIN_NORM);
    float s = tanhf(nn) / nn;
    float bx = b2.x * s, by = b2.y * s;
    float pn = sqrtf(wave_sum(bx * bx + by * by));
    float sc = (pn > MAX_NN) ? MAX_NN / fmaxf(pn, MIN_NORM) : 1.0f;
    bx *= sc; by *= sc;
    float vv = wave_sum(bx * bx + by * by);
    *(float2*)(bh + (size_t)l * D + 2 * lane) = make_float2(bx, by);
    if (lane == 0) vvb[l] = vv;
}

// ---------------- m = (logscale[row] * x[row]) @ W via bf16 MFMA (hi/lo), bf16 output ----
__global__ __launch_bounds__(256, 3) void logmap_gemm(const float* __restrict__ x,
                                                      const float* __restrict__ logscale,
                                                      const float* __restrict__ W,
                                                      unsigned short* __restrict__ m, int n,
                                                      int ntiles) {
    __shared__ char lds[16384];
    const int t = threadIdx.x;
    const int wid = t >> 6, lane = t & 63;
    const int lcol = lane & 15, lkg = lane >> 4;
    const int colbase = wid * 32;

    bf16x8 Bh[4][2], Bl[4][2];
#pragma unroll
    for (int ki = 0; ki < 4; ++ki) {
#pragma unroll
        for (int cf = 0; cf < 2; ++cf) {
            const float* wp = W + (size_t)(ki * 32 + lkg * 8) * D + colbase + cf * 16 + lcol;
#pragma unroll
            for (int e = 0; e < 8; ++e) {
                float f = wp[(size_t)e * D];
                unsigned short h = f2bf(f);
                Bh[ki][cf][e] = (short)h;
                Bl[ki][cf][e] = (short)f2bf(f - bf2f(h));
            }
        }
    }

    for (int tile = blockIdx.x; tile < ntiles; tile += gridDim.x) {
        const int row0 = tile * 32;
        __syncthreads();
#pragma unroll
        for (int p = t; p < 512; p += 256) {
            int fi = p >> 6, ln = p & 63;
            int rf = fi >> 2, ki = fi & 3;
            int row = row0 + rf * 16 + (ln & 15);
            int k0 = ki * 32 + (ln >> 4) * 8;
            float v[8];
            if (row < n) {
                float ls = logscale[row];
                const float* xp = x + (size_t)row * D + k0;
                *(float4*)&v[0] = *(const float4*)xp;
                *(float4*)&v[4] = *(const float4*)(xp + 4);
#pragma unroll
                for (int e = 0; e < 8; ++e) v[e] *= ls;
            } else {
#pragma unroll
                for (int e = 0; e < 8; ++e) v[e] = 0.f;
            }
            bf16x8 hi, lo;
#pragma unroll
            for (int e = 0; e < 8; ++e) {
                unsigned short h = f2bf(v[e]);
                hi[e] = (short)h;
                lo[e] = (short)f2bf(v[e] - bf2f(h));
            }
            *(bf16x8*)(lds + fi * 1024 + ln * 16) = hi;
            *(bf16x8*)(lds + 8192 + fi * 1024 + ln * 16) = lo;
        }
        __syncthreads();

        f32x4 acc[2][2];
#pragma unroll
        for (int rf = 0; rf < 2; ++rf)
#pragma unroll
            for (int cf = 0; cf < 2; ++cf) acc[rf][cf] = (f32x4){0.f, 0.f, 0.f, 0.f};

#pragma unroll
        for (int ki = 0; ki < 4; ++ki) {
            bf16x8 Ah[2], Al[2];
#pragma unroll
            for (int rf = 0; rf < 2; ++rf) {
                Ah[rf] = *(const bf16x8*)(lds + (rf * 4 + ki) * 1024 + lane * 16);
                Al[rf] = *(const bf16x8*)(lds + 8192 + (rf * 4 + ki) * 1024 + lane * 16);
            }
#pragma unroll
            for (int rf = 0; rf < 2; ++rf)
#pragma unroll
                for (int cf = 0; cf < 2; ++cf) {
                    acc[rf][cf] = __builtin_amdgcn_mfma_f32_16x16x32_bf16(Ah[rf], Bh[ki][cf], acc[rf][cf], 0, 0, 0);
                    acc[rf][cf] = __builtin_amdgcn_mfma_f32_16x16x32_bf16(Ah[rf], Bl[ki][cf], acc[rf][cf], 0, 0, 0);
                    acc[rf][cf] = __builtin_amdgcn_mfma_f32_16x16x32_bf16(Al[rf], Bh[ki][cf], acc[rf][cf], 0, 0, 0);
                }
        }

#pragma unroll
        for (int rf = 0; rf < 2; ++rf)
#pragma unroll
            for (int cf = 0; cf < 2; ++cf)
#pragma unroll
                for (int r = 0; r < 4; ++r) {
                    int row = row0 + rf * 16 + lkg * 4 + r;
                    if (row < n)
                        m[(size_t)row * D + colbase + cf * 16 + lcol] = f2bf(acc[rf][cf][r]);
                }
    }
}

// ---------------- aggregate + epilogue: 2 rows per wave (32 lanes x float4 each) -------
__global__ __launch_bounds__(256) void aggregate(const unsigned short* __restrict__ m,
                                                 const int* __restrict__ row_ptr,
                                                 const Edge* __restrict__ eds,
                                                 const float* __restrict__ bh,
                                                 const float* __restrict__ vvb_p,
                                                 float* __restrict__ x,
                                                 float* __restrict__ logscale,
                                                 float* __restrict__ xnorm2,
                                                 int n, int use_act, int last) {
    int wv = (int)((blockIdx.x * (size_t)blockDim.x + threadIdx.x) >> 6);
    int lane = threadIdx.x & 63;
    int half = lane >> 5, li = lane & 31;
    int r = wv * 2 + half;
    if (wv * 2 >= n) return;
    bool active = (r < n);

    int beg = 0, end = 0;
    if (active) { beg = row_ptr[r]; end = row_ptr[r + 1]; }

    const char* mB = (const char*)m + ((size_t)li << 3);
    float a0 = 0.f, a1 = 0.f, a2 = 0.f, a3 = 0.f;
    int e = beg;
    for (; e + 4 <= end; e += 4) {
        Edge e0 = eds[e], e1 = eds[e + 1], e2 = eds[e + 2], e3 = eds[e + 3];
        uint2 g0 = *(const uint2*)(mB + ((size_t)e0.c << 8));
        uint2 g1 = *(const uint2*)(mB + ((size_t)e1.c << 8));
        uint2 g2 = *(const uint2*)(mB + ((size_t)e2.c << 8));
        uint2 g3 = *(const uint2*)(mB + ((size_t)e3.c << 8));
        bf4_fma(g0, e0.v, a0, a1, a2, a3);
        bf4_fma(g1, e1.v, a0, a1, a2, a3);
        bf4_fma(g2, e2.v, a0, a1, a2, a3);
        bf4_fma(g3, e3.v, a0, a1, a2, a3);
    }
    for (; e < end; ++e) {
        Edge ee = eds[e];
        uint2 g = *(const uint2*)(mB + ((size_t)ee.c << 8));
        bf4_fma(g, ee.v, a0, a1, a2, a3);
    }

    float4 bhv = *(const float4*)(bh + 4 * li);
    float vvb = *vvb_p;

    float saa = a0 * a0 + a1 * a1 + a2 * a2 + a3 * a3;
    float sab = a0 * bhv.x + a1 * bhv.y + a2 * bhv.z + a3 * bhv.w;
    gsum2(saa, sab);

    float na = fmaxf(fsqrt_(saa), MIN_NORM);
    float th = tanh_pos(na);
    float s1 = th * frcp(na);
    float nh = th;
    if (th > MAX_NN) { s1 *= MAX_NN * frcp(th); nh = MAX_NN; }
    float h0 = a0 * s1, h1 = a1 * s1, h2_ = a2 * s1, h3_ = a3 * s1;
    float uu = nh * nh;
    float uv = s1 * sab;

    float ca = 1.f + 2.f * uv + vvb;
    float cb = 1.f - uu;
    float den = fmaxf(1.f + 2.f * uv + uu * vvb, MIN_NORM);
    float nsq = fmaxf(ca * ca * uu + 2.f * ca * cb * uv + cb * cb * vvb, 0.f);
    float rden = frcp(den);
    float n2 = fsqrt_(nsq) * rden;
    float s2 = rden;
    if (n2 > MAX_NN) { s2 *= MAX_NN * frcp(n2); n2 = MAX_NN; }
    float p0 = (ca * h0 + cb * bhv.x) * s2;
    float p1 = (ca * h1 + cb * bhv.y) * s2;
    float p2 = (ca * h2_ + cb * bhv.z) * s2;
    float p3 = (ca * h3_ + cb * bhv.w) * s2;

    float4 xo = active ? *(const float4*)(x + (size_t)r * D + 4 * li)
                       : make_float4(0.f, 0.f, 0.f, 0.f);

    float q0, q1, q2, q3, uu3, uv3;
    if (use_act) {
        float nnv = fmaxf(n2, MIN_NORM);
        float nc = fminf(fmaxf(n2, MIN_NORM), MAX_NN);
        float ls2 = atanh_clip(nc) * frcp(nnv);
        float t0 = tanh_sgn(p0 * ls2);
        float t1 = tanh_sgn(p1 * ls2);
        float t2 = tanh_sgn(p2 * ls2);
        float t3 = tanh_sgn(p3 * ls2);
        float stt = t0 * t0 + t1 * t1 + t2 * t2 + t3 * t3;
        float stx = t0 * xo.x + t1 * xo.y + t2 * xo.z + t3 * xo.w;
        gsum2(stt, stx);
        float n3 = fmaxf(fsqrt_(stt), MIN_NORM);
        float th3 = tanh_pos(n3);
        float s3 = th3 * frcp(n3);
        float nh3 = th3;
        if (th3 > MAX_NN) { s3 *= MAX_NN * frcp(th3); nh3 = MAX_NN; }
        q0 = t0 * s3; q1 = t1 * s3; q2 = t2 * s3; q3 = t3 * s3;
        uu3 = nh3 * nh3;
        uv3 = s3 * stx;
    } else {
        float suv = gsum(p0 * xo.x + p1 * xo.y + p2 * xo.z + p3 * xo.w);
        q0 = p0; q1 = p1; q2 = p2; q3 = p3;
        uu3 = n2 * n2;
        uv3 = suv;
    }

    float vv = active ? xnorm2[r] : 0.f;
    ca = 1.f + 2.f * uv3 + vv;
    cb = 1.f - uu3;
    den = fmaxf(1.f + 2.f * uv3 + uu3 * vv, MIN_NORM);
    nsq = fmaxf(ca * ca * uu3 + 2.f * ca * cb * uv3 + cb * cb * vv, 0.f);
    rden = frcp(den);
    float n4 = fsqrt_(nsq) * rden;
    float s4 = rden;
    if (n4 > MAX_NN) { s4 *= MAX_NN * frcp(n4); n4 = MAX_NN; }
    float o0 = (ca * q0 + cb * xo.x) * s4;
    float o1 = (ca * q1 + cb * xo.y) * s4;
    float o2 = (ca * q2 + cb * xo.z) * s4;
    float o3 = (ca * q3 + cb * xo.w) * s4;

    if (active) {
        *(float4*)(x + (size_t)r * D + 4 * li) = make_float4(o0, o1, o2, o3);
        if (li == 0) {
            xnorm2[r] = n4 * n4;
            if (!last) {
                float nnv = fmaxf(n4, MIN_NORM);
                float nc = fminf(fmaxf(n4, MIN_NORM), MAX_NN);
                logscale[r] = atanh_clip(nc) * frcp(nnv);
            }
        }
    }
}

extern "C" void kernel_launch(void* const* d_in, const int* in_sizes, int n_in,
                              void* d_out, int out_size, void* d_ws, size_t ws_size,
                              hipStream_t stream) {
    const float* ent  = (const float*)d_in[0];
    const float* W    = (const float*)d_in[1];
    const float* bias = (const float*)d_in[2];
    const int* rows   = (const int*)d_in[3];
    const int* cols   = (const int*)d_in[4];
    const float* vals = (const float*)d_in[5];
    float* x = (float*)d_out;

    const int n = in_sizes[0] / D;
    const int e = in_sizes[3];
    const int nlayers = in_sizes[1] / (D * D);
    const int npart = (n + ROWS_PER_BLOCK - 1) / ROWS_PER_BLOCK;
    const int ntiles = (n + 31) / 32;

    char* ws = (char*)d_ws;
    size_t off = 0;
    auto alloc = [&](size_t bytes) {
        void* p = ws + off;
        off += (bytes + 255) & ~(size_t)255;
        return p;
    };
    unsigned short* m = (unsigned short*)alloc((size_t)n * D * sizeof(unsigned short));
    float* logscale = (float*)alloc((size_t)n * sizeof(float));
    float* xnorm2   = (float*)alloc((size_t)n * sizeof(float));
    int*   counts   = (int*)alloc((size_t)n * sizeof(int));
    int*   row_ptr  = (int*)alloc((size_t)(n + 1) * sizeof(int));
    int*   cursor   = (int*)alloc((size_t)n * sizeof(int));
    int*   partials = (int*)alloc((size_t)(npart > 1024 ? npart : 1024) * sizeof(int));
    float* bhb      = (float*)alloc((size_t)nlayers * D * sizeof(float));
    float* vvb      = (float*)alloc((size_t)nlayers * sizeof(float));
    Edge*  eds      = (Edge*)alloc((size_t)e * sizeof(Edge));

    hipMemsetAsync(counts, 0, (size_t)n * sizeof(int), stream);
    hist_kernel<<<(e + 255) / 256, 256, 0, stream>>>(rows, counts, e);
    partial_kernel<<<npart, 256, 0, stream>>>(counts, partials, n);
    scan_partials<<<1, 1024, 0, stream>>>(partials, npart);
    rowptr_kernel<<<npart, 256, 0, stream>>>(counts, partials, row_ptr, cursor, n, e);
    scatter_kernel<<<(e + 255) / 256, 256, 0, stream>>>(rows, cols, vals, cursor, eds, e);

    bias_prep<<<nlayers, 64, 0, stream>>>(bias, bhb, vvb);
    proj_init<<<(n + 3) / 4, 256, 0, stream>>>(ent, x, logscale, xnorm2, n);

    for (int l = 0; l < nlayers; ++l) {
        logmap_gemm<<<782, 256, 0, stream>>>(x, logscale, W + (size_t)l * D * D, m, n, ntiles);
        int use_act = (l < nlayers - 1) ? 1 : 0;
        // 4 waves/block, 2 rows/wave -> 8 rows per block
        aggregate<<<(n + 7) / 8, 256, 0, stream>>>(m, row_ptr, eds, bhb + (size_t)l * D,
                                                   vvb + l, x, logscale, xnorm2, n,
                                                   use_act, (l == nlayers - 1) ? 1 : 0);
    }
}